// Round 1
// 178.033 us; speedup vs baseline: 1.0520x; 1.0520x over previous
//
#include <hip/hip_runtime.h>

// BATCH=65536, DIM=512, NUM_CLASSES=1000, NUM_OLD=500
constexpr int kDim = 512;
constexpr int kF4PerRow = kDim / 4;  // 128 float4/row; wave64 -> 2 float4/lane

typedef float f32x4 __attribute__((ext_vector_type(4)));

__device__ __forceinline__ float sqd8(f32x4 e0, f32x4 e1, f32x4 c0, f32x4 c1) {
    f32x4 d0 = e0 - c0;
    f32x4 d1 = e1 - c1;
    f32x4 s  = d0 * d0 + d1 * d1;
    return s.x + s.y + s.z + s.w;
}

__global__ __launch_bounds__(256, 4) void mse_masked_kernel(
    const float* __restrict__ emb,
    const float* __restrict__ cen,
    const int* __restrict__ labels,
    const int* __restrict__ num_old_p,
    int batch,
    float* __restrict__ ws_sum,
    unsigned int* __restrict__ ws_cnt)
{
    const int num_old = *num_old_p;
    const int lane = threadIdx.x & 63;
    const int wid  = threadIdx.x >> 6;   // 4 waves/block share one 64-sample chunk

    const f32x4* __restrict__ emb4 = (const f32x4*)emb;
    const f32x4* __restrict__ cen4 = (const f32x4*)cen;

    float acc = 0.0f;
    unsigned int cnt = 0;

    // Each BLOCK owns 64-sample chunks (grid-strided); the block's 4 waves split
    // the masked rows of each chunk by rank mod 4 -> 4x the wave-parallelism of
    // the previous one-wave-per-chunk scheme.
    for (int c = blockIdx.x; c * 64 < batch; c += gridDim.x) {
        const int chunk = c * 64;
        const int idx = chunk + lane;
        const int mylab = (idx < batch) ? labels[idx] : 0x7fffffff;
        unsigned long long m = __ballot(mylab < num_old);
        if (wid == 0) cnt += (unsigned int)__popcll(m);   // count each sample once

        // Drop the first `wid` set bits: this wave handles ranks wid, wid+4, wid+8, ...
        for (int s = 0; s < wid; ++s) m &= m - 1;

        // Hot path: 4 of this wave's rows at a time (ranks 0,4,8,12 of current m)
        // -> 16 independent 16B loads in flight before any use.
        while (__popcll(m) >= 13) {
            unsigned long long t = m;
            const int b0 = __builtin_ctzll(t);
            t &= t - 1; t &= t - 1; t &= t - 1; t &= t - 1;
            const int b1 = __builtin_ctzll(t);
            t &= t - 1; t &= t - 1; t &= t - 1; t &= t - 1;
            const int b2 = __builtin_ctzll(t);
            t &= t - 1; t &= t - 1; t &= t - 1; t &= t - 1;
            const int b3 = __builtin_ctzll(t);
            t &= t - 1; t &= t - 1; t &= t - 1; t &= t - 1;
            m = t;

            const int l0 = __shfl(mylab, b0, 64);
            const int l1 = __shfl(mylab, b1, 64);
            const int l2 = __shfl(mylab, b2, 64);
            const int l3 = __shfl(mylab, b3, 64);

            const f32x4* e0p = emb4 + (size_t)(chunk + b0) * kF4PerRow;
            const f32x4* e1p = emb4 + (size_t)(chunk + b1) * kF4PerRow;
            const f32x4* e2p = emb4 + (size_t)(chunk + b2) * kF4PerRow;
            const f32x4* e3p = emb4 + (size_t)(chunk + b3) * kF4PerRow;
            const f32x4* c0p = cen4 + (size_t)l0 * kF4PerRow;
            const f32x4* c1p = cen4 + (size_t)l1 * kF4PerRow;
            const f32x4* c2p = cen4 + (size_t)l2 * kF4PerRow;
            const f32x4* c3p = cen4 + (size_t)l3 * kF4PerRow;

            // Embeddings are read exactly once -> non-temporal (don't evict the
            // 2MB centroid set from the 4MB/XCD L2). Centroids: cached loads.
            f32x4 ea0 = __builtin_nontemporal_load(e0p + lane);
            f32x4 eb0 = __builtin_nontemporal_load(e0p + lane + 64);
            f32x4 ea1 = __builtin_nontemporal_load(e1p + lane);
            f32x4 eb1 = __builtin_nontemporal_load(e1p + lane + 64);
            f32x4 ea2 = __builtin_nontemporal_load(e2p + lane);
            f32x4 eb2 = __builtin_nontemporal_load(e2p + lane + 64);
            f32x4 ea3 = __builtin_nontemporal_load(e3p + lane);
            f32x4 eb3 = __builtin_nontemporal_load(e3p + lane + 64);
            f32x4 ca0 = c0p[lane], cb0 = c0p[lane + 64];
            f32x4 ca1 = c1p[lane], cb1 = c1p[lane + 64];
            f32x4 ca2 = c2p[lane], cb2 = c2p[lane + 64];
            f32x4 ca3 = c3p[lane], cb3 = c3p[lane + 64];

            acc += sqd8(ea0, eb0, ca0, cb0);
            acc += sqd8(ea1, eb1, ca1, cb1);
            acc += sqd8(ea2, eb2, ca2, cb2);
            acc += sqd8(ea3, eb3, ca3, cb3);
        }
        // Remainder: rank 0 of current m is always this wave's next row; then
        // advance 4 ranks. (m &= m-1 on m==0 stays 0, so unconditional clears ok.)
        while (m) {
            const int b = __builtin_ctzll(m);
            m &= m - 1; m &= m - 1; m &= m - 1; m &= m - 1;
            const int l = __shfl(mylab, b, 64);
            const f32x4* ep = emb4 + (size_t)(chunk + b) * kF4PerRow;
            const f32x4* cp = cen4 + (size_t)l * kF4PerRow;
            f32x4 e0 = __builtin_nontemporal_load(ep + lane);
            f32x4 e1 = __builtin_nontemporal_load(ep + lane + 64);
            f32x4 c0 = cp[lane], c1 = cp[lane + 64];
            acc += sqd8(e0, e1, c0, c1);
        }
    }

    // Wave butterfly reduce
    #pragma unroll
    for (int off = 32; off > 0; off >>= 1)
        acc += __shfl_xor(acc, off, 64);

    __shared__ float        s_sum[4];
    __shared__ unsigned int s_cnt[4];
    if (lane == 0) { s_sum[wid] = acc; s_cnt[wid] = cnt; }
    __syncthreads();

    if (threadIdx.x == 0) {
        float        bs = 0.0f;
        unsigned int bc = 0u;
        const int wpb = blockDim.x >> 6;
        for (int i = 0; i < wpb; ++i) { bs += s_sum[i]; bc += s_cnt[i]; }
        ws_sum[blockIdx.x] = bs;
        ws_cnt[blockIdx.x] = bc;
    }
}

__global__ __launch_bounds__(256) void finalize_kernel(
    const float* __restrict__ ws_sum,
    const unsigned int* __restrict__ ws_cnt,
    int nparts,
    float* __restrict__ out)
{
    const int t = threadIdx.x;
    float        s = 0.0f;
    unsigned int c = 0u;
    for (int i = t; i < nparts; i += 256) { s += ws_sum[i]; c += ws_cnt[i]; }

    #pragma unroll
    for (int off = 32; off > 0; off >>= 1) {
        s += __shfl_xor(s, off, 64);
        c += __shfl_xor(c, off, 64);
    }
    __shared__ float        ls[4];
    __shared__ unsigned int lc[4];
    const int lane = t & 63, wid = t >> 6;
    if (lane == 0) { ls[wid] = s; lc[wid] = c; }
    __syncthreads();
    if (t == 0) {
        float        ts = ls[0] + ls[1] + ls[2] + ls[3];
        unsigned int tc = lc[0] + lc[1] + lc[2] + lc[3];
        const float total = ts * (1.0f / (float)kDim);
        out[0] = (tc == 0u) ? total : total / (float)tc;
    }
}

extern "C" void kernel_launch(void* const* d_in, const int* in_sizes, int n_in,
                              void* d_out, int out_size, void* d_ws, size_t ws_size,
                              hipStream_t stream) {
    const float* emb       = (const float*)d_in[0];  // [65536, 512] f32
    const float* cen       = (const float*)d_in[1];  // [1000, 512]  f32
    const int*   labels    = (const int*)d_in[2];    // [65536] i32
    const int*   num_old_p = (const int*)d_in[3];    // scalar i32

    const int batch = in_sizes[2];

    int blocks = (batch + 63) / 64;        // one 64-sample chunk per block (4 waves split it)
    if (blocks > 2048) blocks = 2048;      // grid-stride beyond this
    float*        ws_sum = (float*)d_ws;
    unsigned int* ws_cnt = (unsigned int*)((char*)d_ws + blocks * sizeof(float));

    mse_masked_kernel<<<blocks, 256, 0, stream>>>(emb, cen, labels, num_old_p,
                                                  batch, ws_sum, ws_cnt);
    finalize_kernel<<<1, 256, 0, stream>>>(ws_sum, ws_cnt, blocks, (float*)d_out);
}